// Round 5
// baseline (110034.888 us; speedup 1.0000x reference)
//
#include <hip/hip_runtime.h>
#include <hip/hip_bf16.h>
#include <math.h>

// Problem constants
#define BSZ 64
#define TT  512
#define DD  512
#define UU  512
#define NZ  2048   // 4*U

#define NSL    32    // u-slices (workers per batch group)
#define USL    16    // units per slice
#define NBG    4     // batch groups
#define BG     16    // batches per group (= MFMA m)
#define KSTEPS 16    // 512 / 32 (MFMA k=32)
#define FSTRIDE 32   // ints per flag slot = 128 B = one cache line

using short8  = __attribute__((ext_vector_type(8))) short;
using floatx4 = __attribute__((ext_vector_type(4))) float;
typedef unsigned long long u64;

// ---------------------------------------------------------------------------
// Phase 1: zx = x @ Wk.  M=32768, K=512, N=2048. fp32 tiled GEMM (unchanged).
// ---------------------------------------------------------------------------
template <bool ZXBF16>
__global__ __launch_bounds__(256) void gemm_zx(const float* __restrict__ A,
                                               const float* __restrict__ B,
                                               void* __restrict__ Cout) {
  __shared__ float As[16][65];
  __shared__ float Bs[16][64];

  const int tid = threadIdx.x;
  const int tx = tid & 15;
  const int ty = tid >> 4;
  const int m0 = blockIdx.y * 64;
  const int n0 = blockIdx.x * 64;

  const int lm  = tid >> 2;
  const int lk4 = (tid & 3) * 4;
  const int lk  = tid >> 4;
  const int ln4 = (tid & 15) * 4;

  float acc[4][4] = {};

  for (int k0 = 0; k0 < DD; k0 += 16) {
    float4 av = *(const float4*)(A + (size_t)(m0 + lm) * DD + k0 + lk4);
    float4 bv = *(const float4*)(B + (size_t)(k0 + lk) * NZ + n0 + ln4);
    As[lk4 + 0][lm] = av.x;
    As[lk4 + 1][lm] = av.y;
    As[lk4 + 2][lm] = av.z;
    As[lk4 + 3][lm] = av.w;
    *(float4*)&Bs[lk][ln4] = bv;
    __syncthreads();
#pragma unroll
    for (int kk = 0; kk < 16; ++kk) {
      float a[4], b[4];
#pragma unroll
      for (int i = 0; i < 4; ++i) a[i] = As[kk][ty * 4 + i];
#pragma unroll
      for (int j = 0; j < 4; ++j) b[j] = Bs[kk][tx * 4 + j];
#pragma unroll
      for (int i = 0; i < 4; ++i)
#pragma unroll
        for (int j = 0; j < 4; ++j) acc[i][j] = fmaf(a[i], b[j], acc[i][j]);
    }
    __syncthreads();
  }

#pragma unroll
  for (int i = 0; i < 4; ++i) {
    const size_t row = (size_t)(m0 + ty * 4 + i) * NZ + n0 + tx * 4;
    if constexpr (ZXBF16) {
      __hip_bfloat16* C = (__hip_bfloat16*)Cout;
#pragma unroll
      for (int j = 0; j < 4; ++j) C[row + j] = __float2bfloat16(acc[i][j]);
    } else {
      float* C = (float*)Cout;
      *(float4*)&C[row] = make_float4(acc[i][0], acc[i][1], acc[i][2], acc[i][3]);
    }
  }
}

// ---------------------------------------------------------------------------
// Phase 2: ONE persistent kernel, XCD-CLUSTERED (R1/R4-proven skeleton),
// with a HANG-PROOF L2-LOCAL flag fast path.
//
// Evidence so far: R0 spread = 6.9 us/step; R1 clustered + 32 agent flags =
// 8.7; R4 clustered + 1-word agent counter = 9.1. => agent-scope op LATENCY
// (through the XCD port to the coherence point) is the bottleneck, not poll
// volume. This round keeps sync inside the XCD L2:
//  - publish: sc0 store (L1-bypass write-through -> shared L2, ~150cy
//    visibility) AND the proven agent-scope relaxed atomic store to the SAME
//    address/value (guaranteed path).
//  - poll: sc0 loads (L1-bypass, L2-hit) for 2048 spins; then fall back to
//    the proven agent-scope atomic load. CANNOT hang; worst case = R1 perf.
// Ordering: per-wave vmcnt(0) at the post-epilogue __syncthreads drains the
// plain h stores to the shared L2 before tid0 publishes; consumer's h loads
// follow poll + __syncthreads + workgroup acquire fence (R1-proven skeleton).
// ---------------------------------------------------------------------------
__device__ __forceinline__ floatx4 mfma16(short8 a, short8 b, floatx4 c) {
  return __builtin_amdgcn_mfma_f32_16x16x32_bf16(a, b, c, 0, 0, 0);
}

__device__ __forceinline__ int poll_load_l2(const int* p) {
  int v;
  asm volatile("global_load_dword %0, %1, off sc0\n\ts_waitcnt vmcnt(0)"
               : "=&v"(v)
               : "v"(p)
               : "memory");
  return v;
}

__device__ __forceinline__ void flag_store_l2(int* p, int v) {
  asm volatile("global_store_dword %0, %1, off sc0" ::"v"(p), "v"(v)
               : "memory");
}

template <bool ZXBF16>
__global__ __launch_bounds__(256) void lstm_persist(
    const void* __restrict__ zx_, const float* __restrict__ Wr,
    const float* __restrict__ bias, unsigned short* __restrict__ h_hi,
    unsigned short* __restrict__ h_lo, int* __restrict__ flags,
    int* __restrict__ xcd_ctr, float* __restrict__ out) {
  __shared__ int s_role[2];
  extern __shared__ char lds[];
  unsigned short* wr_hi = (unsigned short*)lds;            // [K][g][lane][8]
  unsigned short* wr_lo = wr_hi + KSTEPS * 4 * 64 * 8;     // 32768 ushorts each
  float* z_ex = (float*)(wr_lo + KSTEPS * 4 * 64 * 8);     // [4 g][16 b][16 u]

  const int tid = threadIdx.x;

  // ---- runtime role assignment: cluster by physical XCD (R1/R4-proven) ----
  if (tid == 0) {
    unsigned x;
    asm volatile("s_getreg_b32 %0, hwreg(HW_REG_XCC_ID)" : "=s"(x));
    const int xcd = (int)(x & 7u);
    int slot = NSL;  // default: non-worker
    if (xcd < NBG) slot = atomicAdd(&xcd_ctr[xcd * 16], 1);
    s_role[0] = xcd;
    s_role[1] = slot;
  }
  __syncthreads();
  const int bg = s_role[0];           // batch group = XCD id
  const int sl = s_role[1];           // u-slice = arrival slot on this XCD
  if (bg >= NBG || sl >= NSL) return; // XCDs 4..7 (and any overflow) idle

  const int g = tid >> 6;             // wave = gate 0..3
  const int lane = tid & 63;
  const int u0 = sl * USL;

  // ---- one-time: preformat Wr slice into LDS (split bf16, B-frag order) ----
  {
    const int cidx = tid & 63;        // gg*16+u within slice
    const int koff = tid >> 6;        // 0..3
    const int gg = cidx >> 4, u = cidx & 15;
    const int col = gg * UU + u0 + u;
    for (int k0 = 0; k0 < DD; k0 += 4) {
      const int k = k0 + koff;
      const float v = Wr[(size_t)k * NZ + col];
      const __hip_bfloat16 vh = __float2bfloat16(v);
      const float rem = v - __bfloat162float(vh);
      const __hip_bfloat16 vl = __float2bfloat16(rem);
      const int K = k >> 5, kg = (k >> 3) & 3, j = k & 7;
      const int off = ((K * 4 + gg) * 64 + (kg * 16 + u)) * 8 + j;
      wr_hi[off] = *(const unsigned short*)&vh;
      wr_lo[off] = *(const unsigned short*)&vl;
    }
  }
  __syncthreads();

  // MFMA A-fragment addressing: m = bg*16 + (lane&15), kgroup = lane>>4
  const int am = lane & 15, akg = lane >> 4;
  const size_t arow = (size_t)(bg * BG + am) * UU + akg * 8;  // ushort idx

  // epilogue mapping: thread -> (local batch eb, unit eu)
  const int eb = tid >> 4;            // 0..15
  const int eu = tid & 15;            // 0..15
  const int b = bg * BG + eb;         // global batch
  const float bias_i = bias[0 * UU + u0 + eu];
  const float bias_f = bias[1 * UU + u0 + eu];
  const float bias_g = bias[2 * UU + u0 + eu];
  const float bias_o = bias[3 * UU + u0 + eu];
  float c_state = 0.f;
  const size_t plane_t = (size_t)BSZ * UU;          // 32768 ushorts / timestep
  // packed-pair word index for (b, eu even): (b*UU + u0 + eu)/2
  const int wword = (b * UU + u0 + eu) >> 1;

  int* myflag = flags + (bg * NSL + sl) * FSTRIDE;
  const size_t zbase = (size_t)b * TT;

  // ---- zx(t=0) preload (prefetch pipeline primer) ----
  float zi, zf, zg, zo;
  {
    const size_t zb = zbase * NZ + u0 + eu;
    if constexpr (ZXBF16) {
      const unsigned short* zx = (const unsigned short*)zx_;
      zi = __bfloat162float(*(const __hip_bfloat16*)&zx[zb + 0 * UU]);
      zf = __bfloat162float(*(const __hip_bfloat16*)&zx[zb + 1 * UU]);
      zg = __bfloat162float(*(const __hip_bfloat16*)&zx[zb + 2 * UU]);
      zo = __bfloat162float(*(const __hip_bfloat16*)&zx[zb + 3 * UU]);
    } else {
      const float* zx = (const float*)zx_;
      zi = zx[zb + 0 * UU];
      zf = zx[zb + 1 * UU];
      zg = zx[zb + 2 * UU];
      zo = zx[zb + 3 * UU];
    }
  }

  for (int t = 0; t < TT; ++t) {
    // ---- acquire h_t: fast sc0 poll (L2-local), bounded, agent fallback ----
    if (tid < NSL) {
      const int* fp = flags + (bg * NSL + tid) * FSTRIDE;
      int spins = 0;
      while (true) {
        int v = (spins++ < 2048)
                    ? poll_load_l2(fp)
                    : __hip_atomic_load(fp, __ATOMIC_RELAXED,
                                        __HIP_MEMORY_SCOPE_AGENT);
        if (v >= t) break;
      }
    }
    __syncthreads();
    __builtin_amdgcn_fence(__ATOMIC_ACQUIRE, "workgroup");

    // ---- prefetch zx(t+1) into registers (hidden under the MFMA loop) ----
    float nzi = 0.f, nzf = 0.f, nzg = 0.f, nzo = 0.f;
    if (t + 1 < TT) {
      const size_t zb = (zbase + t + 1) * NZ + u0 + eu;
      if constexpr (ZXBF16) {
        const unsigned short* zx = (const unsigned short*)zx_;
        nzi = __bfloat162float(*(const __hip_bfloat16*)&zx[zb + 0 * UU]);
        nzf = __bfloat162float(*(const __hip_bfloat16*)&zx[zb + 1 * UU]);
        nzg = __bfloat162float(*(const __hip_bfloat16*)&zx[zb + 2 * UU]);
        nzo = __bfloat162float(*(const __hip_bfloat16*)&zx[zb + 3 * UU]);
      } else {
        const float* zx = (const float*)zx_;
        nzi = zx[zb + 0 * UU];
        nzf = zx[zb + 1 * UU];
        nzg = zx[zb + 2 * UU];
        nzo = zx[zb + 3 * UU];
      }
    }

    // ---- z[16b][16u] for gate g via split-bf16 MFMA (h from local L2) ----
    const unsigned short* Ahi = h_hi + (size_t)t * plane_t + arow;
    const unsigned short* Alo = h_lo + (size_t)t * plane_t + arow;
    floatx4 a0 = {0, 0, 0, 0}, a1 = {0, 0, 0, 0}, a2 = {0, 0, 0, 0};
#pragma unroll 4
    for (int K = 0; K < KSTEPS; ++K) {
      const short8 ahi = *(const short8*)(Ahi + K * 32);
      const short8 alo = *(const short8*)(Alo + K * 32);
      const short8 bhi = *(const short8*)(wr_hi + ((K * 4 + g) * 64 + lane) * 8);
      const short8 blo = *(const short8*)(wr_lo + ((K * 4 + g) * 64 + lane) * 8);
      a0 = mfma16(ahi, bhi, a0);
      a1 = mfma16(ahi, blo, a1);
      a2 = mfma16(alo, bhi, a2);
    }
    // C layout: u = lane&15, b-in-tile = (lane>>4)*4 + r
#pragma unroll
    for (int r = 0; r < 4; ++r) {
      const int bb = (lane >> 4) * 4 + r;
      z_ex[(g * 16 + bb) * 16 + (lane & 15)] = a0[r] + a1[r] + a2[r];
    }
    __syncthreads();

    // ---- pointwise gates: thread = (eb, eu) ----
    zi += z_ex[(0 * 16 + eb) * 16 + eu] + bias_i;
    zf += z_ex[(1 * 16 + eb) * 16 + eu] + bias_f;
    zg += z_ex[(2 * 16 + eb) * 16 + eu] + bias_g;
    zo += z_ex[(3 * 16 + eb) * 16 + eu] + bias_o;

    const float ig = 1.f / (1.f + expf(-zi));
    const float fg = 1.f / (1.f + expf(-zf));
    const float gg = tanhf(zg);
    const float og = 1.f / (1.f + expf(-zo));
    c_state = fg * c_state + ig * gg;
    const float hn = og * tanhf(c_state);

    // split-bf16; pack pair-words via shfl, even threads store PLAIN 32-bit
    // words (same-XCD consumers; shared L2 is the coherence point, R1-proven).
    const __hip_bfloat16 hh = __float2bfloat16(hn);
    const float hrem = hn - __bfloat162float(hh);
    const __hip_bfloat16 hl = __float2bfloat16(hrem);
    const unsigned int vhi = (unsigned int)*(const unsigned short*)&hh;
    const unsigned int vlo = (unsigned int)*(const unsigned short*)&hl;
    const unsigned int phi_n = (unsigned int)__shfl_xor((int)vhi, 1);
    const unsigned int plo_n = (unsigned int)__shfl_xor((int)vlo, 1);
    if ((tid & 1) == 0) {
      const unsigned int whi = vhi | (phi_n << 16);
      const unsigned int wlo = vlo | (plo_n << 16);
      unsigned int* phi = (unsigned int*)(h_hi + (size_t)(t + 1) * plane_t) + wword;
      unsigned int* plo = (unsigned int*)(h_lo + (size_t)(t + 1) * plane_t) + wword;
      *phi = whi;
      *plo = wlo;
    }

    if (t == TT - 1) out[(size_t)b * UU + u0 + eu] = hn;

    // rotate zx pipeline
    zi = nzi; zf = nzf; zg = nzg; zo = nzo;

    // ---- release: barrier drains this block's h stores into the shared L2
    //      (vmcnt(0)); tid0 dual-publishes: sc0 (L2 fast path) + agent
    //      atomic (coherence point, guaranteed path). Same addr, same value.
    __syncthreads();
    if (tid == 0) {
      flag_store_l2(myflag, t + 1);
      __hip_atomic_store(myflag, t + 1, __ATOMIC_RELAXED,
                         __HIP_MEMORY_SCOPE_AGENT);
    }
  }
}

// ---------------------------------------------------------------------------
extern "C" void kernel_launch(void* const* d_in, const int* in_sizes, int n_in,
                              void* d_out, int out_size, void* d_ws, size_t ws_size,
                              hipStream_t stream) {
  const float* x    = (const float*)d_in[0];
  const float* Wk   = (const float*)d_in[1];
  const float* Wr   = (const float*)d_in[2];
  const float* bias = (const float*)d_in[3];
  float* out = (float*)d_out;

  const size_t plane_t = (size_t)BSZ * UU;                       // 32768
  const size_t hplane_bytes = (size_t)(TT + 1) * plane_t * 2;    // 32.06 MiB
  const size_t flags_bytes = (size_t)NBG * NSL * FSTRIDE * 4;    // 16 KiB
  const size_t ctr_bytes = (size_t)8 * 16 * 4;                   // 512 B
  const size_t zx_f32_bytes = (size_t)BSZ * TT * NZ * 4;         // 256 MiB

  const size_t need_f32 = zx_f32_bytes + 2 * hplane_bytes + flags_bytes + ctr_bytes;
  const bool use_bf16_zx = (ws_size < need_f32);
  const size_t zx_bytes = use_bf16_zx ? zx_f32_bytes / 2 : zx_f32_bytes;

  char* ws = (char*)d_ws;
  void* zx = (void*)ws;
  unsigned short* h_hi = (unsigned short*)(ws + zx_bytes);
  unsigned short* h_lo = (unsigned short*)(ws + zx_bytes + hplane_bytes);
  int* flags = (int*)(ws + zx_bytes + 2 * hplane_bytes);
  int* xcd_ctr = (int*)(ws + zx_bytes + 2 * hplane_bytes + flags_bytes);

  hipMemsetAsync(h_hi, 0, plane_t * 2, stream);  // h_0 slab
  hipMemsetAsync(h_lo, 0, plane_t * 2, stream);
  hipMemsetAsync(flags, 0, flags_bytes + ctr_bytes, stream);

  dim3 ggrid(NZ / 64, (BSZ * TT) / 64);
  if (use_bf16_zx)
    gemm_zx<true><<<ggrid, 256, 0, stream>>>(x, Wk, zx);
  else
    gemm_zx<false><<<ggrid, 256, 0, stream>>>(x, Wk, zx);

  const int lds_bytes = KSTEPS * 4 * 64 * 8 * 2 * 2 + 4 * 16 * 16 * 4;  // 135168
  dim3 pgrid(256);  // 1 block/CU (LDS-limited) => exactly 32 blocks per XCD
  if (use_bf16_zx) {
    hipFuncSetAttribute(reinterpret_cast<const void*>(lstm_persist<true>),
                        hipFuncAttributeMaxDynamicSharedMemorySize, lds_bytes);
    lstm_persist<true><<<pgrid, 256, lds_bytes, stream>>>(zx, Wr, bias, h_hi, h_lo,
                                                          flags, xcd_ctr, out);
  } else {
    hipFuncSetAttribute(reinterpret_cast<const void*>(lstm_persist<false>),
                        hipFuncAttributeMaxDynamicSharedMemorySize, lds_bytes);
    lstm_persist<false><<<pgrid, 256, lds_bytes, stream>>>(zx, Wr, bias, h_hi, h_lo,
                                                           flags, xcd_ctr, out);
  }
}

// Round 7
// 4704.131 us; speedup vs baseline: 23.3911x; 23.3911x over previous
//
#include <hip/hip_runtime.h>
#include <hip/hip_bf16.h>
#include <math.h>

// Problem constants
#define BSZ 64
#define TT  512
#define DD  512
#define UU  512
#define NZ  2048   // 4*U

#define NSL    32    // u-slices (workers per batch group)
#define USL    16    // units per slice
#define NBG    4     // batch groups
#define BG     16    // batches per group (= MFMA m)
#define KSTEPS 16    // 512 / 32 (MFMA k=32)
#define FSTRIDE 32   // ints per flag slot = 128 B
#define PF     8     // A-load software-pipeline depth

using short8  = __attribute__((ext_vector_type(8))) short;
using floatx4 = __attribute__((ext_vector_type(4))) float;
typedef unsigned long long u64;

// ---------------------------------------------------------------------------
// Phase 1: zx = x @ Wk.  M=32768, K=512, N=2048. fp32 tiled GEMM (unchanged).
// ---------------------------------------------------------------------------
template <bool ZXBF16>
__global__ __launch_bounds__(256) void gemm_zx(const float* __restrict__ A,
                                               const float* __restrict__ B,
                                               void* __restrict__ Cout) {
  __shared__ float As[16][65];
  __shared__ float Bs[16][64];

  const int tid = threadIdx.x;
  const int tx = tid & 15;
  const int ty = tid >> 4;
  const int m0 = blockIdx.y * 64;
  const int n0 = blockIdx.x * 64;

  const int lm  = tid >> 2;
  const int lk4 = (tid & 3) * 4;
  const int lk  = tid >> 4;
  const int ln4 = (tid & 15) * 4;

  float acc[4][4] = {};

  for (int k0 = 0; k0 < DD; k0 += 16) {
    float4 av = *(const float4*)(A + (size_t)(m0 + lm) * DD + k0 + lk4);
    float4 bv = *(const float4*)(B + (size_t)(k0 + lk) * NZ + n0 + ln4);
    As[lk4 + 0][lm] = av.x;
    As[lk4 + 1][lm] = av.y;
    As[lk4 + 2][lm] = av.z;
    As[lk4 + 3][lm] = av.w;
    *(float4*)&Bs[lk][ln4] = bv;
    __syncthreads();
#pragma unroll
    for (int kk = 0; kk < 16; ++kk) {
      float a[4], b[4];
#pragma unroll
      for (int i = 0; i < 4; ++i) a[i] = As[kk][ty * 4 + i];
#pragma unroll
      for (int j = 0; j < 4; ++j) b[j] = Bs[kk][tx * 4 + j];
#pragma unroll
      for (int i = 0; i < 4; ++i)
#pragma unroll
        for (int j = 0; j < 4; ++j) acc[i][j] = fmaf(a[i], b[j], acc[i][j]);
    }
    __syncthreads();
  }

#pragma unroll
  for (int i = 0; i < 4; ++i) {
    const size_t row = (size_t)(m0 + ty * 4 + i) * NZ + n0 + tx * 4;
    if constexpr (ZXBF16) {
      __hip_bfloat16* C = (__hip_bfloat16*)Cout;
#pragma unroll
      for (int j = 0; j < 4; ++j) C[row + j] = __float2bfloat16(acc[i][j]);
    } else {
      float* C = (float*)Cout;
      *(float4*)&C[row] = make_float4(acc[i][0], acc[i][1], acc[i][2], acc[i][3]);
    }
  }
}

// ---------------------------------------------------------------------------
// Phase 2: persistent kernel, R0 SPREAD layout, per-slice DATAFLOW (R6)
// with LINE-EXCLUSIVE h layout (the R6 correctness fix).
//
// R6 failed because gating was per-64B-segment but cache lines are 128B: a
// consumer's verified load fetched a line whose OTHER half belonged to a
// not-yet-published slice-pair -> stale garbage later served from L1/L2.
//
// Fix: h is ONE buffer laid out h[t][b][pair]{hi 64B | lo 64B}. Every
// 128B-aligned line = exactly one (batch row, slice-pair), written only by
// the two producers (2K, 2K+1) whose flags the consumer verifies TOGETHER
// (__any over lane-parity flag loads) before any load of that line. So no
// cache at any level can hold a partially-stale h line. Total bytes and
// per-lane access pattern (16B b128 loads) unchanged.
//
// Dataflow (unchanged from R6): K-step K needs only slices 2K,2K+1. Each
// block starts its K-loop at its OWN slice (always ready) and walks the
// ring; 16 flag loads issued upfront; A-loads software-pipelined PF=8 deep
// so producer waits overlap MFMA compute. Ordering: packed 32-bit agent
// relaxed atomic h-stores, drained by vmcnt(0) at the post-epilogue
// __syncthreads, then tid0 publishes flag=t+1 (agent). Consumer: relaxed
// poll >= t + compiler barrier (in-order issue; loads are control-dependent
// on the poll branch, no speculative vector loads). Deadlock-free: monotone
// flags, inductive progress, all 128 blocks co-resident (1 block/CU).
// ---------------------------------------------------------------------------
__device__ __forceinline__ floatx4 mfma16(short8 a, short8 b, floatx4 c) {
  return __builtin_amdgcn_mfma_f32_16x16x32_bf16(a, b, c, 0, 0, 0);
}

template <bool ZXBF16>
__global__ __launch_bounds__(256) void lstm_persist(
    const void* __restrict__ zx_, const float* __restrict__ Wr,
    const float* __restrict__ bias, unsigned short* __restrict__ h_c,
    int* __restrict__ flags, float* __restrict__ out) {
  extern __shared__ char lds[];
  unsigned short* wr_hi = (unsigned short*)lds;            // [K][g][lane][8]
  unsigned short* wr_lo = wr_hi + KSTEPS * 4 * 64 * 8;     // 32768 ushorts each
  float* z_ex = (float*)(wr_lo + KSTEPS * 4 * 64 * 8);     // [4 g][16 b][16 u]

  const int sl = blockIdx.x;          // u-slice 0..31
  const int bg = blockIdx.y;          // batch group 0..3
  const int tid = threadIdx.x;
  const int g = tid >> 6;             // wave = gate 0..3
  const int lane = tid & 63;
  const int u0 = sl * USL;
  const int K0 = sl >> 1;             // cyclic K-loop start = own slice's step

  // ---- one-time: preformat Wr slice into LDS (split bf16, B-frag order) ----
  {
    const int cidx = tid & 63;        // gg*16+u within slice
    const int koff = tid >> 6;        // 0..3
    const int gg = cidx >> 4, u = cidx & 15;
    const int col = gg * UU + u0 + u;
    for (int k0 = 0; k0 < DD; k0 += 4) {
      const int k = k0 + koff;
      const float v = Wr[(size_t)k * NZ + col];
      const __hip_bfloat16 vh = __float2bfloat16(v);
      const float rem = v - __bfloat162float(vh);
      const __hip_bfloat16 vl = __float2bfloat16(rem);
      const int K = k >> 5, kg = (k >> 3) & 3, j = k & 7;
      const int off = ((K * 4 + gg) * 64 + (kg * 16 + u)) * 8 + j;
      wr_hi[off] = *(const unsigned short*)&vh;
      wr_lo[off] = *(const unsigned short*)&vl;
    }
  }
  __syncthreads();

  // MFMA A-fragment addressing: m = bg*16 + (lane&15), kgroup = lane>>4
  const int am = lane & 15, akg = lane >> 4;
  // h layout (ushort idx): ((t*64 + b)*16 + K)*64 + part*32 + (akg*8 + j)
  // consumer per-lane base for its row:
  const size_t arow_c = (size_t)(bg * BG + am) * (KSTEPS * 64) + akg * 8;
  const size_t plane_c = (size_t)BSZ * KSTEPS * 64;  // 65536 ushorts / step

  // epilogue mapping: thread -> (local batch eb, unit eu)
  const int eb = tid >> 4;            // 0..15
  const int eu = tid & 15;            // 0..15
  const int b = bg * BG + eb;         // global batch
  const float bias_i = bias[0 * UU + u0 + eu];
  const float bias_f = bias[1 * UU + u0 + eu];
  const float bias_g = bias[2 * UU + u0 + eu];
  const float bias_o = bias[3 * UU + u0 + eu];
  float c_state = 0.f;
  const int mypair = sl >> 1;
  // packed-word index within (b,pair) block for even eu:
  // word = part*16 + (sl&1)*8 + eu/2 ; block base (words) computed per t.
  const int wip = ((sl & 1) * 8) + (eu >> 1);

  int* fbase = flags + bg * NSL * FSTRIDE;
  int* myflag = fbase + sl * FSTRIDE;
  const int fpar = lane & 1;          // lane parity -> which flag of the pair
  const size_t zbase = (size_t)b * TT;

  // ---- zx(t=0) preload (prefetch pipeline primer) ----
  float zi, zf, zg, zo;
  {
    const size_t zb = zbase * NZ + u0 + eu;
    if constexpr (ZXBF16) {
      const unsigned short* zx = (const unsigned short*)zx_;
      zi = __bfloat162float(*(const __hip_bfloat16*)&zx[zb + 0 * UU]);
      zf = __bfloat162float(*(const __hip_bfloat16*)&zx[zb + 1 * UU]);
      zg = __bfloat162float(*(const __hip_bfloat16*)&zx[zb + 2 * UU]);
      zo = __bfloat162float(*(const __hip_bfloat16*)&zx[zb + 3 * UU]);
    } else {
      const float* zx = (const float*)zx_;
      zi = zx[zb + 0 * UU];
      zf = zx[zb + 1 * UU];
      zg = zx[zb + 2 * UU];
      zo = zx[zb + 3 * UU];
    }
  }

  for (int t = 0; t < TT; ++t) {
    const unsigned short* Ab = h_c + (size_t)t * plane_c + arow_c;

    // ---- issue all 16 slice-pair flag loads upfront (lat. overlapped) ----
    int fv[KSTEPS];
#pragma unroll
    for (int j = 0; j < KSTEPS; ++j) {
      const int K = (K0 + j) & 15;
      fv[j] = __hip_atomic_load(fbase + (2 * K + fpar) * FSTRIDE,
                                __ATOMIC_RELAXED, __HIP_MEMORY_SCOPE_AGENT);
    }

    // ---- prologue: verify + issue A-loads for the first PF K-steps ----
    short8 ah[PF], al[PF];
#pragma unroll
    for (int p = 0; p < PF; ++p) {
      const int K = (K0 + p) & 15;
      const int* fp = fbase + (2 * K + fpar) * FSTRIDE;
      while (__any(fv[p] < t))
        fv[p] = __hip_atomic_load(fp, __ATOMIC_RELAXED,
                                  __HIP_MEMORY_SCOPE_AGENT);
      asm volatile("" ::: "memory");
      ah[p] = *(const short8*)(Ab + K * 64);
      al[p] = *(const short8*)(Ab + K * 64 + 32);
    }

    // ---- zx(t+1) register prefetch (independent; hides under MFMA) ----
    float nzi = 0.f, nzf = 0.f, nzg = 0.f, nzo = 0.f;
    if (t + 1 < TT) {
      const size_t zb = (zbase + t + 1) * NZ + u0 + eu;
      if constexpr (ZXBF16) {
        const unsigned short* zx = (const unsigned short*)zx_;
        nzi = __bfloat162float(*(const __hip_bfloat16*)&zx[zb + 0 * UU]);
        nzf = __bfloat162float(*(const __hip_bfloat16*)&zx[zb + 1 * UU]);
        nzg = __bfloat162float(*(const __hip_bfloat16*)&zx[zb + 2 * UU]);
        nzo = __bfloat162float(*(const __hip_bfloat16*)&zx[zb + 3 * UU]);
      } else {
        const float* zx = (const float*)zx_;
        nzi = zx[zb + 0 * UU];
        nzf = zx[zb + 1 * UU];
        nzg = zx[zb + 2 * UU];
        nzo = zx[zb + 3 * UU];
      }
    }

    // ---- steady K-loop: MFMA on slice j, prefetch slice j+PF ----
    floatx4 a0 = {0, 0, 0, 0}, a1 = {0, 0, 0, 0}, a2 = {0, 0, 0, 0};
#pragma unroll
    for (int j = 0; j < KSTEPS; ++j) {
      const int K = (K0 + j) & 15;
      const short8 Ah = ah[j & (PF - 1)];     // grab before slot reuse
      const short8 Al = al[j & (PF - 1)];
      if (j + PF < KSTEPS) {
        const int Kp = (K0 + j + PF) & 15;
        const int* fp = fbase + (2 * Kp + fpar) * FSTRIDE;
        while (__any(fv[j + PF] < t))
          fv[j + PF] = __hip_atomic_load(fp, __ATOMIC_RELAXED,
                                         __HIP_MEMORY_SCOPE_AGENT);
        asm volatile("" ::: "memory");
        ah[j & (PF - 1)] = *(const short8*)(Ab + Kp * 64);
        al[j & (PF - 1)] = *(const short8*)(Ab + Kp * 64 + 32);
      }
      const short8 bhi = *(const short8*)(wr_hi + ((K * 4 + g) * 64 + lane) * 8);
      const short8 blo = *(const short8*)(wr_lo + ((K * 4 + g) * 64 + lane) * 8);
      a0 = mfma16(Ah, bhi, a0);
      a1 = mfma16(Ah, blo, a1);
      a2 = mfma16(Al, bhi, a2);
    }

    // C layout: u = lane&15, b-in-tile = (lane>>4)*4 + r
#pragma unroll
    for (int r = 0; r < 4; ++r) {
      const int bb = (lane >> 4) * 4 + r;
      z_ex[(g * 16 + bb) * 16 + (lane & 15)] = a0[r] + a1[r] + a2[r];
    }
    __syncthreads();

    // ---- pointwise gates: thread = (eb, eu) ----
    zi += z_ex[(0 * 16 + eb) * 16 + eu] + bias_i;
    zf += z_ex[(1 * 16 + eb) * 16 + eu] + bias_f;
    zg += z_ex[(2 * 16 + eb) * 16 + eu] + bias_g;
    zo += z_ex[(3 * 16 + eb) * 16 + eu] + bias_o;

    const float ig = 1.f / (1.f + expf(-zi));
    const float fg = 1.f / (1.f + expf(-zf));
    const float gg = tanhf(zg);
    const float og = 1.f / (1.f + expf(-zo));
    c_state = fg * c_state + ig * gg;
    const float hn = og * tanhf(c_state);

    // split-bf16; pack pair-words via shfl, even threads store packed 32-bit
    // agent-scope RELAXED atomics into the LINE-EXCLUSIVE layout.
    const __hip_bfloat16 hh = __float2bfloat16(hn);
    const float hrem = hn - __bfloat162float(hh);
    const __hip_bfloat16 hl = __float2bfloat16(hrem);
    const unsigned int vhi = (unsigned int)*(const unsigned short*)&hh;
    const unsigned int vlo = (unsigned int)*(const unsigned short*)&hl;
    const unsigned int phi_n = (unsigned int)__shfl_xor((int)vhi, 1);
    const unsigned int plo_n = (unsigned int)__shfl_xor((int)vlo, 1);
    if ((tid & 1) == 0) {
      const unsigned int whi = vhi | (phi_n << 16);
      const unsigned int wlo = vlo | (plo_n << 16);
      // (b,pair) block base in 32-bit words: ((t+1)*64 + b)*16*32 + pair*32
      unsigned int* blk = (unsigned int*)h_c +
                          (((size_t)(t + 1) * BSZ + b) * KSTEPS + mypair) * 32;
      __hip_atomic_store(blk + wip, whi, __ATOMIC_RELAXED,
                         __HIP_MEMORY_SCOPE_AGENT);
      __hip_atomic_store(blk + 16 + wip, wlo, __ATOMIC_RELAXED,
                         __HIP_MEMORY_SCOPE_AGENT);
    }

    if (t == TT - 1) out[(size_t)b * UU + u0 + eu] = hn;

    // rotate zx pipeline
    zi = nzi; zf = nzf; zg = nzg; zo = nzo;

    // ---- release: barrier drains ALL waves' h stores (vmcnt(0) at barrier),
    //      then tid0 publishes flag = t+1 (agent scope, R0-proven). ----
    __syncthreads();
    if (tid == 0)
      __hip_atomic_store(myflag, t + 1, __ATOMIC_RELAXED,
                         __HIP_MEMORY_SCOPE_AGENT);
  }
}

// ---------------------------------------------------------------------------
extern "C" void kernel_launch(void* const* d_in, const int* in_sizes, int n_in,
                              void* d_out, int out_size, void* d_ws, size_t ws_size,
                              hipStream_t stream) {
  const float* x    = (const float*)d_in[0];
  const float* Wk   = (const float*)d_in[1];
  const float* Wr   = (const float*)d_in[2];
  const float* bias = (const float*)d_in[3];
  float* out = (float*)d_out;

  const size_t plane_bytes = (size_t)BSZ * KSTEPS * 128;         // 131072
  const size_t h_bytes = (size_t)(TT + 1) * plane_bytes;         // 64.1 MiB
  const size_t flags_bytes = (size_t)NBG * NSL * FSTRIDE * 4;    // 16 KiB
  const size_t zx_f32_bytes = (size_t)BSZ * TT * NZ * 4;         // 256 MiB

  const size_t need_f32 = zx_f32_bytes + h_bytes + flags_bytes;
  const bool use_bf16_zx = (ws_size < need_f32);
  const size_t zx_bytes = use_bf16_zx ? zx_f32_bytes / 2 : zx_f32_bytes;

  char* ws = (char*)d_ws;
  void* zx = (void*)ws;
  unsigned short* h_c = (unsigned short*)(ws + zx_bytes);
  int* flags = (int*)(ws + zx_bytes + h_bytes);

  hipMemsetAsync(h_c, 0, plane_bytes, stream);  // h_0 plane
  hipMemsetAsync(flags, 0, flags_bytes, stream);

  dim3 ggrid(NZ / 64, (BSZ * TT) / 64);
  if (use_bf16_zx)
    gemm_zx<true><<<ggrid, 256, 0, stream>>>(x, Wk, zx);
  else
    gemm_zx<false><<<ggrid, 256, 0, stream>>>(x, Wk, zx);

  const int lds_bytes = KSTEPS * 4 * 64 * 8 * 2 * 2 + 4 * 16 * 16 * 4;  // 135168
  dim3 pgrid(NSL, NBG);  // spread layout (R0, best measured)
  if (use_bf16_zx) {
    hipFuncSetAttribute(reinterpret_cast<const void*>(lstm_persist<true>),
                        hipFuncAttributeMaxDynamicSharedMemorySize, lds_bytes);
    lstm_persist<true><<<pgrid, 256, lds_bytes, stream>>>(zx, Wr, bias, h_c,
                                                          flags, out);
  } else {
    hipFuncSetAttribute(reinterpret_cast<const void*>(lstm_persist<false>),
                        hipFuncAttributeMaxDynamicSharedMemorySize, lds_bytes);
    lstm_persist<false><<<pgrid, 256, lds_bytes, stream>>>(zx, Wr, bias, h_c,
                                                           flags, out);
  }
}